// Round 1
// baseline (521.310 us; speedup 1.0000x reference)
//
#include <hip/hip_runtime.h>
#include <math.h>

#define D_CH 2048
#define NS 64
#define LSEQ 8192
#define TCH 64
#define NCHUNK (LSEQ / TCH)   // 128
#define KSLAB 512             // K-split for U GEMM (4 slabs)

// ---------------------------------------------------------------------------
// 64x64 matmul helper on LDS buffers, result in registers.
// Thread layout: mi = tid>>2 (row), mj0 = (tid&3)*16 (16-col group).
// ---------------------------------------------------------------------------
__device__ __forceinline__ void mm64r(const float* Xb, int xs, const float* Yb,
                                      float* acc, int mi, int mj0) {
#pragma unroll
  for (int t = 0; t < 16; ++t) acc[t] = 0.f;
#pragma unroll 4
  for (int k4 = 0; k4 < 16; ++k4) {
    float4 a4 = *(const float4*)&Xb[mi * xs + 4 * k4];
#pragma unroll
    for (int kk = 0; kk < 4; ++kk) {
      float a = (kk == 0) ? a4.x : (kk == 1) ? a4.y : (kk == 2) ? a4.z : a4.w;
      const float* yr = &Yb[(4 * k4 + kk) * 64 + mj0];
      float4 y0 = *(const float4*)&yr[0];
      float4 y1 = *(const float4*)&yr[4];
      float4 y2 = *(const float4*)&yr[8];
      float4 y3 = *(const float4*)&yr[12];
      acc[0]  += a * y0.x; acc[1]  += a * y0.y; acc[2]  += a * y0.z; acc[3]  += a * y0.w;
      acc[4]  += a * y1.x; acc[5]  += a * y1.y; acc[6]  += a * y1.z; acc[7]  += a * y1.w;
      acc[8]  += a * y2.x; acc[9]  += a * y2.y; acc[10] += a * y2.z; acc[11] += a * y2.w;
      acc[12] += a * y3.x; acc[13] += a * y3.y; acc[14] += a * y3.z; acc[15] += a * y3.w;
    }
  }
}

// ---------------------------------------------------------------------------
// prep: delta = exp(log_delta); inv = (I - d/2 A)^-1 (Gauss-Jordan, no pivot:
// M strictly diag-dominant); invd = delta*inv; dA = inv(I + d/2 A);
// dA64 = dA^64; dA512 = dA^512.
// ---------------------------------------------------------------------------
__global__ __launch_bounds__(256) void prep_kernel(const float* __restrict__ A,
                                                   const float* __restrict__ logd,
                                                   float* __restrict__ invd,
                                                   float* __restrict__ dAg,
                                                   float* __restrict__ dA64g,
                                                   float* __restrict__ dA512g) {
  __shared__ float buf[12288];           // 48 KB
  float* aug = buf;                      // 64 x 128 (stride 128)
  float* T1  = buf + 8192;               // 64 x 64
  const int tid = threadIdx.x;
  const float delta = expf(logd[0]);
  const float half = 0.5f * delta;
  const int ibase = tid >> 7;            // 0 or 1
  const int j = tid & 127;

  // build augmented [I - half*A | I]
  for (int idx = tid; idx < 8192; idx += 256) {
    int i = idx >> 7, c = idx & 127;
    float v;
    if (c < 64) v = (c == i ? 1.f : 0.f) - half * A[i * 64 + c];
    else        v = ((c - 64) == i ? 1.f : 0.f);
    aug[idx] = v;
  }
  __syncthreads();

  // Gauss-Jordan without pivoting
  for (int k = 0; k < 64; ++k) {
    float pinv = 1.0f / aug[k * 128 + k];
    __syncthreads();
    if (tid < 128) aug[k * 128 + tid] *= pinv;
    __syncthreads();
    float f[32];
#pragma unroll
    for (int m = 0; m < 32; ++m) f[m] = aug[(ibase + 2 * m) * 128 + k];
    __syncthreads();
    float pr = aug[k * 128 + j];
#pragma unroll
    for (int m = 0; m < 32; ++m) {
      int i = ibase + 2 * m;
      if (i != k) aug[i * 128 + j] -= f[m] * pr;
    }
    __syncthreads();
  }

  // write invd (delta*inv) and build T1 = I + half*A
  for (int idx = tid; idx < 4096; idx += 256) {
    int i = idx >> 6, c = idx & 63;
    invd[idx] = delta * aug[i * 128 + 64 + c];
    T1[idx] = (i == c ? 1.f : 0.f) + half * A[idx];
  }
  __syncthreads();

  const int mi = tid >> 2, mj0 = (tid & 3) << 4;
  float acc[16];

  // dA = inv @ T1
  mm64r(aug + 64, 128, T1, acc, mi, mj0);
  __syncthreads();                       // all reads of aug/T1 done
  float* p = buf;                        // dA lives at buf[0..4096)
  float* q = buf + 4096;
#pragma unroll
  for (int t = 0; t < 16; ++t) {
    p[mi * 64 + mj0 + t] = acc[t];
    dAg[mi * 64 + mj0 + t] = acc[t];
  }
  __syncthreads();

  // repeated squaring: s=5 -> dA^64, s=8 -> dA^512
  for (int s = 0; s < 9; ++s) {
    mm64r(p, 64, p, acc, mi, mj0);
    __syncthreads();
#pragma unroll
    for (int t = 0; t < 16; ++t) q[mi * 64 + mj0 + t] = acc[t];
    if (s == 5) {
#pragma unroll
      for (int t = 0; t < 16; ++t) dA64g[mi * 64 + mj0 + t] = acc[t];
    }
    if (s == 8) {
#pragma unroll
      for (int t = 0; t < 16; ++t) dA512g[mi * 64 + mj0 + t] = acc[t];
    }
    __syncthreads();
    float* tmp = p; p = q; q = tmp;
  }
}

// ---------------------------------------------------------------------------
// dB = invd @ B   (64 x 2048), invd = delta*inv
// ---------------------------------------------------------------------------
__global__ __launch_bounds__(256) void dB_kernel(const float* __restrict__ B,
                                                 const float* __restrict__ invd,
                                                 float* __restrict__ dB) {
  __shared__ float inv_s[4096];
  const int tid = threadIdx.x;
  const int d = blockIdx.x * 256 + tid;
  for (int idx = tid; idx < 4096; idx += 256) inv_s[idx] = invd[idx];
  __syncthreads();
  float bcol[64];
#pragma unroll 8
  for (int k = 0; k < 64; ++k) bcol[k] = B[k * D_CH + d];
#pragma unroll 2
  for (int n = 0; n < 64; ++n) {
    float acc = 0.f;
#pragma unroll
    for (int k = 0; k < 64; k += 4) {
      float4 w = *(const float4*)&inv_s[n * 64 + k];
      acc += w.x * bcol[k] + w.y * bcol[k + 1] + w.z * bcol[k + 2] + w.w * bcol[k + 3];
    }
    dB[n * D_CH + d] = acc;
  }
}

// ---------------------------------------------------------------------------
// U(t,n) = sum_d dB(n,d) * X(d,t).  U stored (L,64). K-split with atomics.
// grid: (t-tiles = 128, k-slabs = 4), 256 threads.
// ---------------------------------------------------------------------------
__global__ __launch_bounds__(256) void u_gemm_kernel(const float* __restrict__ X,
                                                     const float* __restrict__ dB,
                                                     float* __restrict__ U) {
  __shared__ float Xs[64 * 64];          // [k][t]
  __shared__ float Bs[64 * 65];          // [n][k], padded
  const int tid = threadIdx.x;
  const int t0 = blockIdx.x * 64;
  const int k0 = blockIdx.y * KSLAB;
  const int tx = tid & 63;               // n
  const int ty = tid >> 6;               // t-group (0..3)
  float acc[16];
#pragma unroll
  for (int i = 0; i < 16; ++i) acc[i] = 0.f;

  for (int kk = 0; kk < KSLAB; kk += 64) {
#pragma unroll
    for (int it = 0; it < 16; ++it) {
      int idx = it * 256 + tid;
      int r = idx >> 6, c = idx & 63;
      Xs[r * 64 + c] = X[(size_t)(k0 + kk + r) * LSEQ + t0 + c];
      Bs[r * 65 + c] = dB[r * D_CH + (k0 + kk + c)];
    }
    __syncthreads();
#pragma unroll 4
    for (int k = 0; k < 64; ++k) {
      float b = Bs[tx * 65 + k];
      const float* xr = &Xs[k * 64 + ty * 16];
#pragma unroll
      for (int i = 0; i < 16; i += 4) {
        float4 x4 = *(const float4*)&xr[i];
        acc[i]     += b * x4.x;
        acc[i + 1] += b * x4.y;
        acc[i + 2] += b * x4.z;
        acc[i + 3] += b * x4.w;
      }
    }
    __syncthreads();
  }
#pragma unroll
  for (int i = 0; i < 16; ++i)
    atomicAdd(&U[(size_t)(t0 + ty * 16 + i) * 64 + tx], acc[i]);
}

// ---------------------------------------------------------------------------
// Generic chunk scan. One wave (64 threads) per block; matvec via __shfl.
// h_{t} = M @ h_{t-1} + in_t.
//   WRITE_ALL=false: write only final h (chunk summary) to out[c*64+..]
//   WRITE_ALL=true, EXCLUSIVE=true:  write h BEFORE each step (prefix states)
//   WRITE_ALL=true, EXCLUSIVE=false: write h AFTER each step (full states)
// ---------------------------------------------------------------------------
template <int T, bool WRITE_ALL, bool EXCLUSIVE>
__global__ __launch_bounds__(64) void scan_kernel(const float* __restrict__ in,
                                                  const float* __restrict__ M,
                                                  const float* __restrict__ Hin,
                                                  float* __restrict__ out) {
  const int tid = threadIdx.x;
  const int c = blockIdx.x;
  float ar[64];
#pragma unroll
  for (int jj = 0; jj < 64; jj += 4) {
    float4 v = *(const float4*)&M[tid * 64 + jj];
    ar[jj] = v.x; ar[jj + 1] = v.y; ar[jj + 2] = v.z; ar[jj + 3] = v.w;
  }
  float h = Hin ? Hin[c * 64 + tid] : 0.f;
  const float* inc = in + (size_t)c * T * 64;
  float* outc = out + (size_t)c * (WRITE_ALL ? T * 64 : 64);

  for (int t = 0; t < T; ++t) {
    if (WRITE_ALL && EXCLUSIVE) outc[t * 64 + tid] = h;
    float u = inc[t * 64 + tid];
    float a0 = u, a1 = 0.f, a2 = 0.f, a3 = 0.f;
#pragma unroll
    for (int jj = 0; jj < 64; jj += 4) {
      a0 += ar[jj]     * __shfl(h, jj);
      a1 += ar[jj + 1] * __shfl(h, jj + 1);
      a2 += ar[jj + 2] * __shfl(h, jj + 2);
      a3 += ar[jj + 3] * __shfl(h, jj + 3);
    }
    h = (a0 + a1) + (a2 + a3);
    if (WRITE_ALL && !EXCLUSIVE) outc[t * 64 + tid] = h;
  }
  if (!WRITE_ALL) outc[tid] = h;
}

// ---------------------------------------------------------------------------
// Y(d,t) = sum_n C(d,n) * Ht(t,n) + Dp(d)*X(d,t)
// grid: (t-tiles = 128, d-tiles = 32), 256 threads; 16 outputs/thread.
// ---------------------------------------------------------------------------
__global__ __launch_bounds__(256) void out_kernel(const float* __restrict__ X,
                                                  const float* __restrict__ C,
                                                  const float* __restrict__ Dp,
                                                  const float* __restrict__ Ht,
                                                  float* __restrict__ Y) {
  __shared__ float Cs[64 * 64];          // [d_local][n]
  __shared__ float Hs[64 * 68];          // [t_local][n], padded to 68 (16B align)
  const int tid = threadIdx.x;
  const int t0 = blockIdx.x * 64;
  const int d0 = blockIdx.y * 64;
  const int tx = tid & 63;               // t_local
  const int ty = tid >> 6;               // d-group

#pragma unroll
  for (int it = 0; it < 16; ++it) {
    int idx = it * 256 + tid;
    int r = idx >> 6, c = idx & 63;
    Cs[r * 64 + c] = C[(d0 + r) * 64 + c];
    Hs[r * 68 + c] = Ht[(size_t)(t0 + r) * 64 + c];
  }
  __syncthreads();

  float acc[16];
#pragma unroll
  for (int i = 0; i < 16; ++i) acc[i] = 0.f;
#pragma unroll
  for (int n4 = 0; n4 < 16; ++n4) {
    float4 h4 = *(const float4*)&Hs[tx * 68 + n4 * 4];
#pragma unroll
    for (int i = 0; i < 16; ++i) {
      float4 c4 = *(const float4*)&Cs[(ty * 16 + i) * 64 + n4 * 4];
      acc[i] += c4.x * h4.x + c4.y * h4.y + c4.z * h4.z + c4.w * h4.w;
    }
  }
#pragma unroll
  for (int i = 0; i < 16; ++i) {
    int d = d0 + ty * 16 + i;
    size_t off = (size_t)d * LSEQ + t0 + tx;
    Y[off] = acc[i] + Dp[d] * X[off];
  }
}

// ---------------------------------------------------------------------------
extern "C" void kernel_launch(void* const* d_in, const int* in_sizes, int n_in,
                              void* d_out, int out_size, void* d_ws, size_t ws_size,
                              hipStream_t stream) {
  const float* X  = (const float*)d_in[0];
  const float* A  = (const float*)d_in[1];
  const float* B  = (const float*)d_in[2];
  const float* C  = (const float*)d_in[3];
  const float* Dp = (const float*)d_in[4];
  const float* ld = (const float*)d_in[5];
  float* out = (float*)d_out;
  float* ws = (float*)d_ws;

  float* invd  = ws;             // 4096
  float* dA    = ws + 4096;      // 4096
  float* dA64  = ws + 8192;      // 4096
  float* dA512 = ws + 12288;     // 4096
  float* dB    = ws + 16384;     // 131072
  float* U     = ws + 147456;    // 524288  (L,64)
  float* S     = ws + 671744;    // 8192    (128,64) level-1 summaries
  float* S2    = ws + 679936;    // 1024    (16,64)  level-2 summaries
  float* H2    = ws + 680960;    // 1024    (16,64)  level-2 prefix states
  float* Hinit = ws + 681984;    // 8192    (128,64) level-1 prefix states
  float* Ht    = ws + 690176;    // 524288  (L,64)   full states
  // total: 1214464 floats = ~4.6 MB

  hipMemsetAsync(U, 0, 524288 * sizeof(float), stream);
  prep_kernel<<<1, 256, 0, stream>>>(A, ld, invd, dA, dA64, dA512);
  dB_kernel<<<8, 256, 0, stream>>>(B, invd, dB);
  u_gemm_kernel<<<dim3(128, 4), 256, 0, stream>>>(X, dB, U);
  // level-1 chunk summaries (128 chunks of 64)
  scan_kernel<TCH, false, false><<<NCHUNK, 64, 0, stream>>>(U, dA, nullptr, S);
  // level-2 summaries (16 chunks of 8)
  scan_kernel<8, false, false><<<16, 64, 0, stream>>>(S, dA64, nullptr, S2);
  // top scan: prefix states of level-2 chunks
  scan_kernel<16, true, true><<<1, 64, 0, stream>>>(S2, dA512, nullptr, H2);
  // expand level-2 -> level-1 prefix states
  scan_kernel<8, true, true><<<16, 64, 0, stream>>>(S, dA64, H2, Hinit);
  // expand level-1 -> full per-step states
  scan_kernel<TCH, true, false><<<NCHUNK, 64, 0, stream>>>(U, dA, Hinit, Ht);
  out_kernel<<<dim3(128, 32), 256, 0, stream>>>(X, C, Dp, Ht, out);
}

// Round 2
// 404.956 us; speedup vs baseline: 1.2873x; 1.2873x over previous
//
#include <hip/hip_runtime.h>
#include <math.h>

#define D_CH 2048
#define NS 64
#define LSEQ 8192
#define TCH 64
#define NCHUNK (LSEQ / TCH)   // 128
#define KS 1024               // K per slab (2 slabs)
#define SLAB (LSEQ * 64)      // U slab stride in floats

// ---------------------------------------------------------------------------
// 4x4-register-tile 64x64 matmul helpers on LDS (stride 64).
// Mapping: r0 = (tid>>4)*4 (4 unique/wave -> broadcast X reads),
//          c0 = (tid&15)*4 (16 unique -> bank-group-balanced Y reads).
// ---------------------------------------------------------------------------
__device__ __forceinline__ void mmzero(float acc[16]) {
#pragma unroll
  for (int t = 0; t < 16; ++t) acc[t] = 0.f;
}

__device__ __forceinline__ void mmld(float acc[16], const float* __restrict__ Z,
                                     int r0, int c0) {
#pragma unroll
  for (int i = 0; i < 4; ++i) {
    float4 z = *(const float4*)&Z[(r0 + i) * 64 + c0];
    acc[i * 4 + 0] = z.x; acc[i * 4 + 1] = z.y;
    acc[i * 4 + 2] = z.z; acc[i * 4 + 3] = z.w;
  }
}

__device__ __forceinline__ void mm64_mac(const float* __restrict__ Xb,
                                         const float* __restrict__ Yb,
                                         float acc[16], int r0, int c0) {
#pragma unroll 4
  for (int k = 0; k < 64; k += 4) {
    float4 x0 = *(const float4*)&Xb[(r0 + 0) * 64 + k];
    float4 x1 = *(const float4*)&Xb[(r0 + 1) * 64 + k];
    float4 x2 = *(const float4*)&Xb[(r0 + 2) * 64 + k];
    float4 x3 = *(const float4*)&Xb[(r0 + 3) * 64 + k];
    float4 y0 = *(const float4*)&Yb[(k + 0) * 64 + c0];
    float4 y1 = *(const float4*)&Yb[(k + 1) * 64 + c0];
    float4 y2 = *(const float4*)&Yb[(k + 2) * 64 + c0];
    float4 y3 = *(const float4*)&Yb[(k + 3) * 64 + c0];
#define MROW(i, xi) \
    acc[i * 4 + 0] += xi.x * y0.x + xi.y * y1.x + xi.z * y2.x + xi.w * y3.x; \
    acc[i * 4 + 1] += xi.x * y0.y + xi.y * y1.y + xi.z * y2.y + xi.w * y3.y; \
    acc[i * 4 + 2] += xi.x * y0.z + xi.y * y1.z + xi.z * y2.z + xi.w * y3.z; \
    acc[i * 4 + 3] += xi.x * y0.w + xi.y * y1.w + xi.z * y2.w + xi.w * y3.w;
    MROW(0, x0) MROW(1, x1) MROW(2, x2) MROW(3, x3)
#undef MROW
  }
}

__device__ __forceinline__ void mmst(float* Dst, const float acc[16], int r0, int c0) {
#pragma unroll
  for (int i = 0; i < 4; ++i)
    *(float4*)&Dst[(r0 + i) * 64 + c0] =
        make_float4(acc[i * 4 + 0], acc[i * 4 + 1], acc[i * 4 + 2], acc[i * 4 + 3]);
}

// ---------------------------------------------------------------------------
// prep: P = (delta/2)A.  inv(I-P) = sum P^k via Q16 = (I+P)(I+P^2)(I+P^4)(I+P^8)
// (||P|| <= ~0.12 -> truncation ~1e-15).  dA = 2*Q - I.  invd = delta*Q.
// Then 9 squarings: dA^2..dA^512 (write dA^64, dA^512).
// 15 matmuls total, ~1 barrier each.
// ---------------------------------------------------------------------------
__global__ __launch_bounds__(256) void prep_kernel(const float* __restrict__ A,
                                                   const float* __restrict__ logd,
                                                   float* __restrict__ invd,
                                                   float* __restrict__ dAg,
                                                   float* __restrict__ dA64g,
                                                   float* __restrict__ dA512g) {
  __shared__ float B0[4096], B1[4096], B2[4096], B3[4096], B4[4096];
  const int tid = threadIdx.x;
  const int r0 = (tid >> 4) * 4, c0 = (tid & 15) * 4;
  const float delta = expf(logd[0]);
  const float half = 0.5f * delta;
  float acc[16], acc2[16];

  // B0 = P, B3 = Q1 = I + P
  for (int idx = tid; idx < 4096; idx += 256) {
    float p = half * A[idx];
    B0[idx] = p;
    B3[idx] = p + ((idx >> 6) == (idx & 63) ? 1.f : 0.f);
  }
  __syncthreads();

  // B1 = P^2
  mmzero(acc); mm64_mac(B0, B0, acc, r0, c0); mmst(B1, acc, r0, c0);
  __syncthreads();

  // B4 = Q2 = Q1 + P2*Q1 ; B2 = P4 = P2*P2   (reads B1,B3; writes B4,B2)
  mmld(acc, B3, r0, c0); mm64_mac(B1, B3, acc, r0, c0);
  mmzero(acc2); mm64_mac(B1, B1, acc2, r0, c0);
  mmst(B4, acc, r0, c0); mmst(B2, acc2, r0, c0);
  __syncthreads();

  // B3 = Q4 = Q2 + P4*Q2 ; B0 = P8 = P4*P4   (reads B2,B4; writes B3,B0)
  mmld(acc, B4, r0, c0); mm64_mac(B2, B4, acc, r0, c0);
  mmzero(acc2); mm64_mac(B2, B2, acc2, r0, c0);
  mmst(B3, acc, r0, c0); mmst(B0, acc2, r0, c0);
  __syncthreads();

  // B4 = Q8 = Q4 + P8*Q4   (reads B0,B3; writes B4)
  mmld(acc, B3, r0, c0); mm64_mac(B0, B3, acc, r0, c0);
  mmst(B4, acc, r0, c0);
  __syncthreads();

  // elementwise: invd = delta*Q ; dA = 2Q - I -> B0 + global
  for (int idx = tid; idx < 4096; idx += 256) {
    float qv = B4[idx];
    invd[idx] = delta * qv;
    float da = 2.f * qv - ((idx >> 6) == (idx & 63) ? 1.f : 0.f);
    B0[idx] = da;
    dAg[idx] = da;
  }
  __syncthreads();

  // squarings: s=6 -> dA^64, s=9 -> dA^512
  float* p = B0;
  float* q = B1;
  for (int s = 1; s <= 9; ++s) {
    mmzero(acc); mm64_mac(p, p, acc, r0, c0);
    mmst(q, acc, r0, c0);
    if (s == 6) mmst(dA64g, acc, r0, c0);
    if (s == 9) mmst(dA512g, acc, r0, c0);
    __syncthreads();
    float* t = p; p = q; q = t;
  }
}

// ---------------------------------------------------------------------------
// dBt[d][n] = delta * (inv @ B)[n][d]   (transposed for u_gemm staging)
// ---------------------------------------------------------------------------
__global__ __launch_bounds__(256) void dB_kernel(const float* __restrict__ B,
                                                 const float* __restrict__ invd,
                                                 float* __restrict__ dBt) {
  __shared__ float inv_s[4096];
  const int tid = threadIdx.x;
  const int d = blockIdx.x * 256 + tid;
  for (int idx = tid; idx < 4096; idx += 256) inv_s[idx] = invd[idx];
  __syncthreads();
  float bcol[64];
#pragma unroll
  for (int k = 0; k < 64; ++k) bcol[k] = B[k * D_CH + d];
#pragma unroll 2
  for (int n = 0; n < 64; n += 4) {
    float a0 = 0.f, a1 = 0.f, a2 = 0.f, a3 = 0.f;
#pragma unroll
    for (int k = 0; k < 64; k += 4) {
      float4 w0 = *(const float4*)&inv_s[(n + 0) * 64 + k];
      float4 w1 = *(const float4*)&inv_s[(n + 1) * 64 + k];
      float4 w2 = *(const float4*)&inv_s[(n + 2) * 64 + k];
      float4 w3 = *(const float4*)&inv_s[(n + 3) * 64 + k];
      a0 += w0.x * bcol[k] + w0.y * bcol[k + 1] + w0.z * bcol[k + 2] + w0.w * bcol[k + 3];
      a1 += w1.x * bcol[k] + w1.y * bcol[k + 1] + w1.z * bcol[k + 2] + w1.w * bcol[k + 3];
      a2 += w2.x * bcol[k] + w2.y * bcol[k + 1] + w2.z * bcol[k + 2] + w2.w * bcol[k + 3];
      a3 += w3.x * bcol[k] + w3.y * bcol[k + 1] + w3.z * bcol[k + 2] + w3.w * bcol[k + 3];
    }
    *(float4*)&dBt[(size_t)d * 64 + n] = make_float4(a0, a1, a2, a3);
  }
}

// ---------------------------------------------------------------------------
// U[slab][t][n] = sum_{k in slab} X[k][t] * dBt[k][n].
// grid (128 t-tiles, 2 slabs). 4x4 register tiles, double-buffered staging.
// ---------------------------------------------------------------------------
__global__ __launch_bounds__(256) void u_gemm_kernel(const float* __restrict__ X,
                                                     const float* __restrict__ dBt,
                                                     float* __restrict__ U) {
  __shared__ float Xs[2][4096];
  __shared__ float Bs[2][4096];
  const int tid = threadIdx.x;
  const int t0 = blockIdx.x * 64;
  const int k0 = blockIdx.y * KS;
  const int tq = (tid >> 4) * 4;   // 4 unique/wave -> broadcast X reads
  const int nq = (tid & 15) * 4;   // 16 unique -> balanced B reads
  float acc[16];
  mmzero(acc);
  float4 xr[4], br[4];

  // fetch + stash tile 0
#pragma unroll
  for (int it = 0; it < 4; ++it) {
    int idx = it * 256 + tid;
    int r = idx >> 4, c4 = (idx & 15) * 4;
    xr[it] = *(const float4*)&X[(size_t)(k0 + r) * LSEQ + t0 + c4];
    br[it] = *(const float4*)&dBt[(size_t)(k0 + r) * 64 + c4];
  }
#pragma unroll
  for (int it = 0; it < 4; ++it) {
    int idx = it * 256 + tid;
    int r = idx >> 4, c4 = (idx & 15) * 4;
    *(float4*)&Xs[0][r * 64 + c4] = xr[it];
    *(float4*)&Bs[0][r * 64 + c4] = br[it];
  }

  int buf = 0;
  for (int kk = 0; kk < KS; kk += 64) {
    if (kk + 64 < KS) {
#pragma unroll
      for (int it = 0; it < 4; ++it) {
        int idx = it * 256 + tid;
        int r = idx >> 4, c4 = (idx & 15) * 4;
        xr[it] = *(const float4*)&X[(size_t)(k0 + kk + 64 + r) * LSEQ + t0 + c4];
        br[it] = *(const float4*)&dBt[(size_t)(k0 + kk + 64 + r) * 64 + c4];
      }
    }
    __syncthreads();
    const float* Xb = Xs[buf];
    const float* Bb = Bs[buf];
#pragma unroll 8
    for (int k = 0; k < 64; ++k) {
      float4 xv = *(const float4*)&Xb[k * 64 + tq];
      float4 bv = *(const float4*)&Bb[k * 64 + nq];
      acc[0]  += xv.x * bv.x; acc[1]  += xv.x * bv.y; acc[2]  += xv.x * bv.z; acc[3]  += xv.x * bv.w;
      acc[4]  += xv.y * bv.x; acc[5]  += xv.y * bv.y; acc[6]  += xv.y * bv.z; acc[7]  += xv.y * bv.w;
      acc[8]  += xv.z * bv.x; acc[9]  += xv.z * bv.y; acc[10] += xv.z * bv.z; acc[11] += xv.z * bv.w;
      acc[12] += xv.w * bv.x; acc[13] += xv.w * bv.y; acc[14] += xv.w * bv.z; acc[15] += xv.w * bv.w;
    }
    if (kk + 64 < KS) {
#pragma unroll
      for (int it = 0; it < 4; ++it) {
        int idx = it * 256 + tid;
        int r = idx >> 4, c4 = (idx & 15) * 4;
        *(float4*)&Xs[buf ^ 1][r * 64 + c4] = xr[it];
        *(float4*)&Bs[buf ^ 1][r * 64 + c4] = br[it];
      }
    }
    buf ^= 1;
  }
  float* Us = U + (size_t)blockIdx.y * SLAB;
#pragma unroll
  for (int i = 0; i < 4; ++i)
    *(float4*)&Us[(size_t)(t0 + tq + i) * 64 + nq] =
        make_float4(acc[i * 4 + 0], acc[i * 4 + 1], acc[i * 4 + 2], acc[i * 4 + 3]);
}

// ---------------------------------------------------------------------------
// Scan: one wave/block; h' = M h + u via LDS-broadcast matvec (16 b128
// broadcast reads/step instead of 64 dependent bpermutes). Ping-pong h buffer.
// ---------------------------------------------------------------------------
template <int NSLAB>
__device__ __forceinline__ float loadu(const float* __restrict__ inc, int t, int tid) {
  float u = inc[t * 64 + tid];
  if (NSLAB == 2) u += inc[(size_t)SLAB + t * 64 + tid];
  return u;
}

template <int T, int NSLAB, bool WRITE_ALL, bool EXCLUSIVE>
__global__ __launch_bounds__(64) void scan_kernel(const float* __restrict__ in,
                                                  const float* __restrict__ M,
                                                  const float* __restrict__ Hin,
                                                  float* __restrict__ out) {
  __shared__ float hs[2][64];
  const int tid = threadIdx.x;
  const int c = blockIdx.x;
  float ar[64];
#pragma unroll
  for (int jj = 0; jj < 64; jj += 4) {
    float4 v = *(const float4*)&M[tid * 64 + jj];
    ar[jj] = v.x; ar[jj + 1] = v.y; ar[jj + 2] = v.z; ar[jj + 3] = v.w;
  }
  float h = Hin ? Hin[c * 64 + tid] : 0.f;
  hs[0][tid] = h;
  const float* inc = in + (size_t)c * T * 64;
  float* outc = out + (size_t)c * (WRITE_ALL ? T * 64 : 64);
  float unext = loadu<NSLAB>(inc, 0, tid);

  for (int t = 0; t < T; ++t) {
    if (WRITE_ALL && EXCLUSIVE) outc[t * 64 + tid] = h;
    float u = unext;
    if (t + 1 < T) unext = loadu<NSLAB>(inc, t + 1, tid);
    const float* hb = hs[t & 1];
    float a0 = u, a1 = 0.f, a2 = 0.f, a3 = 0.f;
#pragma unroll
    for (int jj = 0; jj < 64; jj += 4) {
      float4 hv = *(const float4*)&hb[jj];
      a0 += ar[jj + 0] * hv.x;
      a1 += ar[jj + 1] * hv.y;
      a2 += ar[jj + 2] * hv.z;
      a3 += ar[jj + 3] * hv.w;
    }
    h = (a0 + a1) + (a2 + a3);
    hs[(t + 1) & 1][tid] = h;
    if (WRITE_ALL && !EXCLUSIVE) outc[t * 64 + tid] = h;
  }
  if (!WRITE_ALL) outc[tid] = h;
}

// ---------------------------------------------------------------------------
// Y[d][t] = sum_n C[d][n]*Ht[t][n] + Dp[d]*X[d][t].
// Cs in [d][n] (natural); Hs transposed to [n][t] (stride 68) so the inner
// loop is 8 b128 per 64 FMA and stores stay t-coalesced.
// ---------------------------------------------------------------------------
__global__ __launch_bounds__(256) void out_kernel(const float* __restrict__ X,
                                                  const float* __restrict__ C,
                                                  const float* __restrict__ Dp,
                                                  const float* __restrict__ Ht,
                                                  float* __restrict__ Y) {
  __shared__ float Cs[4096];        // [d][n]
  __shared__ float Hs[64 * 68];     // [n][t]
  const int tid = threadIdx.x;
  const int t0 = blockIdx.x * 64;
  const int d0 = blockIdx.y * 64;
  const int tq = (tid & 15) * 4;    // t fast across lanes -> coalesced stores
  const int dq = (tid >> 4) * 4;

#pragma unroll
  for (int it = 0; it < 4; ++it) {
    int idx = it * 256 + tid;
    int r = idx >> 4, c4 = (idx & 15) * 4;
    *(float4*)&Cs[r * 64 + c4] = *(const float4*)&C[(size_t)(d0 + r) * 64 + c4];
    float4 h = *(const float4*)&Ht[(size_t)(t0 + r) * 64 + c4];
    Hs[(c4 + 0) * 68 + r] = h.x;
    Hs[(c4 + 1) * 68 + r] = h.y;
    Hs[(c4 + 2) * 68 + r] = h.z;
    Hs[(c4 + 3) * 68 + r] = h.w;
  }
  __syncthreads();

  float acc[16];
  mmzero(acc);
#pragma unroll 4
  for (int n = 0; n < 64; n += 4) {
    float4 h0 = *(const float4*)&Hs[(n + 0) * 68 + tq];
    float4 h1 = *(const float4*)&Hs[(n + 1) * 68 + tq];
    float4 h2 = *(const float4*)&Hs[(n + 2) * 68 + tq];
    float4 h3 = *(const float4*)&Hs[(n + 3) * 68 + tq];
    float4 cv0 = *(const float4*)&Cs[(dq + 0) * 64 + n];
    float4 cv1 = *(const float4*)&Cs[(dq + 1) * 64 + n];
    float4 cv2 = *(const float4*)&Cs[(dq + 2) * 64 + n];
    float4 cv3 = *(const float4*)&Cs[(dq + 3) * 64 + n];
#define OROW(i, ci) \
    acc[i * 4 + 0] += ci.x * h0.x + ci.y * h1.x + ci.z * h2.x + ci.w * h3.x; \
    acc[i * 4 + 1] += ci.x * h0.y + ci.y * h1.y + ci.z * h2.y + ci.w * h3.y; \
    acc[i * 4 + 2] += ci.x * h0.z + ci.y * h1.z + ci.z * h2.z + ci.w * h3.z; \
    acc[i * 4 + 3] += ci.x * h0.w + ci.y * h1.w + ci.z * h2.w + ci.w * h3.w;
    OROW(0, cv0) OROW(1, cv1) OROW(2, cv2) OROW(3, cv3)
#undef OROW
  }

#pragma unroll
  for (int i = 0; i < 4; ++i) {
    int d = d0 + dq + i;
    size_t off = (size_t)d * LSEQ + t0 + tq;
    float4 x4 = *(const float4*)&X[off];
    float dp = Dp[d];
    *(float4*)&Y[off] = make_float4(acc[i * 4 + 0] + dp * x4.x,
                                    acc[i * 4 + 1] + dp * x4.y,
                                    acc[i * 4 + 2] + dp * x4.z,
                                    acc[i * 4 + 3] + dp * x4.w);
  }
}

// ---------------------------------------------------------------------------
extern "C" void kernel_launch(void* const* d_in, const int* in_sizes, int n_in,
                              void* d_out, int out_size, void* d_ws, size_t ws_size,
                              hipStream_t stream) {
  const float* X  = (const float*)d_in[0];
  const float* A  = (const float*)d_in[1];
  const float* B  = (const float*)d_in[2];
  const float* C  = (const float*)d_in[3];
  const float* Dp = (const float*)d_in[4];
  const float* ld = (const float*)d_in[5];
  float* out = (float*)d_out;
  float* ws = (float*)d_ws;

  float* invd  = ws;               // 4096
  float* dA    = ws + 4096;        // 4096
  float* dA64  = ws + 8192;        // 4096
  float* dA512 = ws + 12288;       // 4096
  float* dBt   = ws + 16384;       // 131072 (2048 x 64)
  float* U     = ws + 147456;      // 2 x 524288 (slabs)
  float* S     = ws + 1196032;     // 8192
  float* S2    = ws + 1204224;     // 1024
  float* H2    = ws + 1205248;     // 1024
  float* Hinit = ws + 1206272;     // 8192
  float* Ht    = ws + 1214464;     // 524288
  // total 1738752 floats = 6.95 MB

  prep_kernel<<<1, 256, 0, stream>>>(A, ld, invd, dA, dA64, dA512);
  dB_kernel<<<8, 256, 0, stream>>>(B, invd, dBt);
  u_gemm_kernel<<<dim3(128, 2), 256, 0, stream>>>(X, dBt, U);
  scan_kernel<TCH, 2, false, false><<<NCHUNK, 64, 0, stream>>>(U, dA, nullptr, S);
  scan_kernel<8, 1, false, false><<<16, 64, 0, stream>>>(S, dA64, nullptr, S2);
  scan_kernel<16, 1, true, true><<<1, 64, 0, stream>>>(S2, dA512, nullptr, H2);
  scan_kernel<8, 1, true, true><<<16, 64, 0, stream>>>(S, dA64, H2, Hinit);
  scan_kernel<TCH, 2, true, false><<<NCHUNK, 64, 0, stream>>>(U, dA, Hinit, Ht);
  out_kernel<<<dim3(128, 32), 256, 0, stream>>>(X, C, Dp, Ht, out);
}

// Round 4
// 295.890 us; speedup vs baseline: 1.7618x; 1.3686x over previous
//
#include <hip/hip_runtime.h>
#include <math.h>

#define D_CH 2048
#define LSEQ 8192
#define T1 32
#define NC1 256          // LSEQ / T1
#define KSLAB 512
#define NSLAB 4

// ---------------------------------------------------------------------------
// 4x4-register-tile 64x64x64 matmul helpers on LDS, template strides.
// r0=(tid>>4)*4 (broadcast rows), c0=(tid&15)*4 (consecutive -> conflict-free)
// ---------------------------------------------------------------------------
__device__ __forceinline__ void mmzero(float acc[16]) {
#pragma unroll
  for (int t = 0; t < 16; ++t) acc[t] = 0.f;
}

template <int SZ>
__device__ __forceinline__ void mmld(float acc[16], const float* __restrict__ Z,
                                     int r0, int c0) {
#pragma unroll
  for (int i = 0; i < 4; ++i) {
    float4 z = *(const float4*)&Z[(r0 + i) * SZ + c0];
    acc[i * 4 + 0] = z.x; acc[i * 4 + 1] = z.y;
    acc[i * 4 + 2] = z.z; acc[i * 4 + 3] = z.w;
  }
}

template <int SX, int SY>
__device__ __forceinline__ void mac44(float acc[16], const float* __restrict__ Xb,
                                      const float* __restrict__ Yb, int r0, int c0) {
#pragma unroll 4
  for (int k = 0; k < 64; k += 4) {
    float4 x0 = *(const float4*)&Xb[(r0 + 0) * SX + k];
    float4 x1 = *(const float4*)&Xb[(r0 + 1) * SX + k];
    float4 x2 = *(const float4*)&Xb[(r0 + 2) * SX + k];
    float4 x3 = *(const float4*)&Xb[(r0 + 3) * SX + k];
    float4 y0 = *(const float4*)&Yb[(k + 0) * SY + c0];
    float4 y1 = *(const float4*)&Yb[(k + 1) * SY + c0];
    float4 y2 = *(const float4*)&Yb[(k + 2) * SY + c0];
    float4 y3 = *(const float4*)&Yb[(k + 3) * SY + c0];
#define MROW(i, xi) \
    acc[i * 4 + 0] += xi.x * y0.x + xi.y * y1.x + xi.z * y2.x + xi.w * y3.x; \
    acc[i * 4 + 1] += xi.x * y0.y + xi.y * y1.y + xi.z * y2.y + xi.w * y3.y; \
    acc[i * 4 + 2] += xi.x * y0.z + xi.y * y1.z + xi.z * y2.z + xi.w * y3.z; \
    acc[i * 4 + 3] += xi.x * y0.w + xi.y * y1.w + xi.z * y2.w + xi.w * y3.w;
    MROW(0, x0) MROW(1, x1) MROW(2, x2) MROW(3, x3)
#undef MROW
  }
}

template <int SZ>
__device__ __forceinline__ void mmst(float* Dst, const float acc[16], int r0, int c0) {
#pragma unroll
  for (int i = 0; i < 4; ++i)
    *(float4*)&Dst[(r0 + i) * SZ + c0] =
        make_float4(acc[i * 4 + 0], acc[i * 4 + 1], acc[i * 4 + 2], acc[i * 4 + 3]);
}

// ---------------------------------------------------------------------------
// B-transpose: Bt[d][n] = B[n][d]
// ---------------------------------------------------------------------------
__global__ __launch_bounds__(256) void bt_kernel(const float* __restrict__ B,
                                                 float* __restrict__ Bt) {
  __shared__ float Ts[64 * 65];
  const int tid = threadIdx.x;
  const int d0 = blockIdx.x * 64;
#pragma unroll
  for (int it = 0; it < 16; ++it) {
    int idx = it * 256 + tid;
    int n = idx >> 6, d = idx & 63;
    Ts[n * 65 + d] = B[(size_t)n * D_CH + d0 + d];
  }
  __syncthreads();
#pragma unroll
  for (int it = 0; it < 16; ++it) {
    int idx = it * 256 + tid;
    int d = idx >> 6, n = idx & 63;
    Bt[(size_t)(d0 + d) * 64 + n] = Ts[n * 65 + d];
  }
}

// ---------------------------------------------------------------------------
// main_kernel: block 0 = prep (Q-chain inverse + dA powers), blocks 1..512 =
// V = B @ X (slab-split, atomicAdd into V). Runs concurrently on one launch.
// prep: P = (d/2)A; Q = (I+P)(I+P^2)(I+P^4)(I+P^8) ~= inv(I-P) (||P||<=0.12,
// err ~1e-15). dA = 2Q - I. invdT[m][n] = delta*Q[n][m]. dA^32, dA^512 taps.
// ---------------------------------------------------------------------------
__global__ __launch_bounds__(256) void main_kernel(const float* __restrict__ X,
                                                   const float* __restrict__ A,
                                                   const float* __restrict__ Bt,
                                                   const float* __restrict__ logd,
                                                   float* __restrict__ invdT,
                                                   float* __restrict__ dAg,
                                                   float* __restrict__ dA32g,
                                                   float* __restrict__ dA512g,
                                                   float* __restrict__ V) {
  __shared__ float smem[13056];          // prep: 3 x 64x68; vgemm: 2 x 4096
  const int tid = threadIdx.x;

  if (blockIdx.x == 0) {
    // ------------------------------ prep ---------------------------------
    float* b0 = smem;
    float* b1 = smem + 4352;
    float* b2 = smem + 8704;
    const int r0 = (tid >> 4) * 4, c0 = (tid & 15) * 4;
    const float delta = expf(logd[0]);
    const float half = 0.5f * delta;
    float acc[16], acc2[16];

    for (int idx = tid; idx < 4096; idx += 256) {
      int i = idx >> 6, j = idx & 63;
      float p = half * A[idx];
      b0[i * 68 + j] = p;
      b2[i * 68 + j] = p + (i == j ? 1.f : 0.f);
    }
    __syncthreads();

    // b1 = P^2
    mmzero(acc); mac44<68, 68>(acc, b0, b0, r0, c0);
    mmst<68>(b1, acc, r0, c0);
    __syncthreads();

    // Q2 = Q1 + P2*Q1 -> b0 ; P4 = P2*P2 -> b2 (in-place after reads)
    mmld<68>(acc, b2, r0, c0); mac44<68, 68>(acc, b1, b2, r0, c0);
    mmzero(acc2); mac44<68, 68>(acc2, b1, b1, r0, c0);
    __syncthreads();
    mmst<68>(b0, acc, r0, c0); mmst<68>(b2, acc2, r0, c0);
    __syncthreads();

    // Q4 = Q2 + P4*Q2 -> b1 ; P8 = P4*P4 -> b2
    mmld<68>(acc, b0, r0, c0); mac44<68, 68>(acc, b2, b0, r0, c0);
    mmzero(acc2); mac44<68, 68>(acc2, b2, b2, r0, c0);
    __syncthreads();
    mmst<68>(b1, acc, r0, c0); mmst<68>(b2, acc2, r0, c0);
    __syncthreads();

    // Q8 = Q4 + P8*Q4 -> b0
    mmld<68>(acc, b1, r0, c0); mac44<68, 68>(acc, b2, b1, r0, c0);
    __syncthreads();
    mmst<68>(b0, acc, r0, c0);
    __syncthreads();

    // elementwise: invdT = delta*Q^T ; dA = 2Q - I -> b1 + global
    for (int idx = tid; idx < 4096; idx += 256) {
      int n = idx >> 6, m = idx & 63;
      float qv = b0[n * 68 + m];
      invdT[m * 64 + n] = delta * qv;
      float da = 2.f * qv - (n == m ? 1.f : 0.f);
      b1[n * 68 + m] = da;
      dAg[idx] = da;
    }
    __syncthreads();

    // squarings: s=5 -> dA^32, s=9 -> dA^512
    float* p = b1;
    float* q = b2;
    for (int s = 1; s <= 9; ++s) {
      mmzero(acc); mac44<68, 68>(acc, p, p, r0, c0);
      if (s == 5) mmst<64>(dA32g, acc, r0, c0);
      if (s == 9) mmst<64>(dA512g, acc, r0, c0);
      mmst<68>(q, acc, r0, c0);
      __syncthreads();
      float* t = p; p = q; q = t;
    }
  } else {
    // ------------------------------ vgemm --------------------------------
    float* Xs = smem;                    // [k][t] 64x64
    float* Bs = smem + 4096;             // [k][n] 64x64
    const int b = blockIdx.x - 1;
    const int t0 = (b & 127) * 64;
    const int k0 = (b >> 7) * KSLAB;
    const int tq = (tid >> 4) * 4;       // broadcast t-rows
    const int nq = (tid & 15) * 4;
    float acc[16];
    mmzero(acc);

    for (int kk = 0; kk < KSLAB; kk += 64) {
      __syncthreads();
#pragma unroll
      for (int it = 0; it < 4; ++it) {
        int idx = it * 256 + tid;
        int r = idx >> 4, c4 = (idx & 15) * 4;
        *(float4*)&Xs[r * 64 + c4] =
            *(const float4*)&X[(size_t)(k0 + kk + r) * LSEQ + t0 + c4];
        *(float4*)&Bs[r * 64 + c4] =
            *(const float4*)&Bt[(size_t)(k0 + kk + r) * 64 + c4];
      }
      __syncthreads();
#pragma unroll 8
      for (int k = 0; k < 64; ++k) {
        float4 xv = *(const float4*)&Xs[k * 64 + tq];
        float4 bv = *(const float4*)&Bs[k * 64 + nq];
        acc[0]  += xv.x * bv.x; acc[1]  += xv.x * bv.y; acc[2]  += xv.x * bv.z; acc[3]  += xv.x * bv.w;
        acc[4]  += xv.y * bv.x; acc[5]  += xv.y * bv.y; acc[6]  += xv.y * bv.z; acc[7]  += xv.y * bv.w;
        acc[8]  += xv.z * bv.x; acc[9]  += xv.z * bv.y; acc[10] += xv.z * bv.z; acc[11] += xv.z * bv.w;
        acc[12] += xv.w * bv.x; acc[13] += xv.w * bv.y; acc[14] += xv.w * bv.z; acc[15] += xv.w * bv.w;
      }
    }
#pragma unroll
    for (int i = 0; i < 4; ++i)
#pragma unroll
      for (int j = 0; j < 4; ++j)
        atomicAdd(&V[(size_t)(t0 + tq + i) * 64 + nq + j], acc[i * 4 + j]);
  }
}

// ---------------------------------------------------------------------------
// U[t][n] = sum_m invdT[m][n] * V[t][m]
// ---------------------------------------------------------------------------
__global__ __launch_bounds__(256) void u_transform(const float* __restrict__ V,
                                                   const float* __restrict__ invdT,
                                                   float* __restrict__ U) {
  __shared__ float Vs[64 * 68];
  __shared__ float Ws[64 * 68];
  const int tid = threadIdx.x;
  const int t0 = blockIdx.x * 64;
  const int tq = (tid >> 4) * 4, nq = (tid & 15) * 4;
#pragma unroll
  for (int it = 0; it < 4; ++it) {
    int idx = it * 256 + tid;
    int r = idx >> 4, c4 = (idx & 15) * 4;
    *(float4*)&Vs[r * 68 + c4] = *(const float4*)&V[(size_t)(t0 + r) * 64 + c4];
    *(float4*)&Ws[r * 68 + c4] = *(const float4*)&invdT[r * 64 + c4];
  }
  __syncthreads();
  float acc[16];
  mmzero(acc);
  mac44<68, 68>(acc, Vs, Ws, tq, nq);
#pragma unroll
  for (int i = 0; i < 4; ++i)
    *(float4*)&U[(size_t)(t0 + tq + i) * 64 + nq] =
        make_float4(acc[i * 4 + 0], acc[i * 4 + 1], acc[i * 4 + 2], acc[i * 4 + 3]);
}

// ---------------------------------------------------------------------------
// matvec step: h' = M h + u, h broadcast via LDS ping-pong
// ---------------------------------------------------------------------------
__device__ __forceinline__ float matvec(const float ar[64], const float* __restrict__ hb,
                                        float u) {
  float a0 = u, a1 = 0.f, a2 = 0.f, a3 = 0.f;
#pragma unroll
  for (int jj = 0; jj < 64; jj += 4) {
    float4 hv = *(const float4*)&hb[jj];
    a0 += ar[jj + 0] * hv.x;
    a1 += ar[jj + 1] * hv.y;
    a2 += ar[jj + 2] * hv.z;
    a3 += ar[jj + 3] * hv.w;
  }
  return (a0 + a1) + (a2 + a3);
}

// ---------------------------------------------------------------------------
// scan: one wave/block; 4-deep global prefetch ring.
// ---------------------------------------------------------------------------
template <int T, bool WRITE_ALL, bool EXCLUSIVE>
__global__ __launch_bounds__(64) void scan_kernel(const float* __restrict__ in,
                                                  const float* __restrict__ M,
                                                  const float* __restrict__ Hin,
                                                  float* __restrict__ out) {
  __shared__ float hs[2][64];
  const int tid = threadIdx.x;
  const int c = blockIdx.x;
  float ar[64];
#pragma unroll
  for (int jj = 0; jj < 64; jj += 4) {
    float4 v = *(const float4*)&M[tid * 64 + jj];
    ar[jj] = v.x; ar[jj + 1] = v.y; ar[jj + 2] = v.z; ar[jj + 3] = v.w;
  }
  float h = Hin ? Hin[c * 64 + tid] : 0.f;
  hs[0][tid] = h;
  const float* inc = in + (size_t)c * T * 64;
  float* outc = out + (size_t)c * (WRITE_ALL ? T * 64 : 64);
  float up[4];
#pragma unroll
  for (int i = 0; i < 4; ++i) up[i] = (i < T) ? inc[i * 64 + tid] : 0.f;

  for (int t = 0; t < T; ++t) {
    if (WRITE_ALL && EXCLUSIVE) outc[t * 64 + tid] = h;
    float u = up[t & 3];
    if (t + 4 < T) up[t & 3] = inc[(t + 4) * 64 + tid];
    h = matvec(ar, hs[t & 1], u);
    hs[(t + 1) & 1][tid] = h;
    if (WRITE_ALL && !EXCLUSIVE) outc[t * 64 + tid] = h;
  }
  if (!WRITE_ALL) outc[tid] = h;
}

// ---------------------------------------------------------------------------
// mid: all 3 middle levels in one block (16 waves).
//  A: wave w: summary of S[w*16..w*16+16) with dA32 -> S2s
//  B: wave 0: exclusive scan of S2s with dA512 -> H2s
//  C: wave w: exclusive expand within its chunk -> Hinit (global)
// ---------------------------------------------------------------------------
__global__ __launch_bounds__(1024) void mid_kernel(const float* __restrict__ S,
                                                   const float* __restrict__ dA32,
                                                   const float* __restrict__ dA512,
                                                   float* __restrict__ Hinit) {
  __shared__ float S2s[1024];
  __shared__ float H2s[1024];
  __shared__ float hsbuf[2048];
  const int tid = threadIdx.x;
  const int wave = tid >> 6, lane = tid & 63;
  float* hs0 = &hsbuf[wave * 128];
  float* hs1 = hs0 + 64;
  float ar[64];
#pragma unroll
  for (int jj = 0; jj < 64; jj += 4) {
    float4 v = *(const float4*)&dA32[lane * 64 + jj];
    ar[jj] = v.x; ar[jj + 1] = v.y; ar[jj + 2] = v.z; ar[jj + 3] = v.w;
  }
  const float* inw = S + wave * 16 * 64;

  // phase A
  float h = 0.f;
  hs0[lane] = 0.f;
  for (int t = 0; t < 16; ++t) {
    float u = inw[t * 64 + lane];
    h = matvec(ar, (t & 1) ? hs1 : hs0, u);
    ((t & 1) ? hs0 : hs1)[lane] = h;
  }
  S2s[wave * 64 + lane] = h;
  __syncthreads();

  // phase B (wave 0 only)
  if (wave == 0) {
    float br[64];
#pragma unroll
    for (int jj = 0; jj < 64; jj += 4) {
      float4 v = *(const float4*)&dA512[lane * 64 + jj];
      br[jj] = v.x; br[jj + 1] = v.y; br[jj + 2] = v.z; br[jj + 3] = v.w;
    }
    float g = 0.f;
    hs0[lane] = 0.f;
    for (int t = 0; t < 16; ++t) {
      H2s[t * 64 + lane] = g;
      float u = S2s[t * 64 + lane];
      g = matvec(br, (t & 1) ? hs1 : hs0, u);
      ((t & 1) ? hs0 : hs1)[lane] = g;
    }
  }
  __syncthreads();

  // phase C
  h = H2s[wave * 64 + lane];
  hs0[lane] = h;
  for (int t = 0; t < 16; ++t) {
    Hinit[(wave * 16 + t) * 64 + lane] = h;
    float u = inw[t * 64 + lane];
    h = matvec(ar, (t & 1) ? hs1 : hs0, u);
    ((t & 1) ? hs0 : hs1)[lane] = h;
  }
}

// ---------------------------------------------------------------------------
// Y[d][t] = sum_n C[d][n]*Ht[t][n] + Dp[d]*X[d][t]  (Hs transposed in LDS)
// ---------------------------------------------------------------------------
__global__ __launch_bounds__(256) void out_kernel(const float* __restrict__ X,
                                                  const float* __restrict__ C,
                                                  const float* __restrict__ Dp,
                                                  const float* __restrict__ Ht,
                                                  float* __restrict__ Y) {
  __shared__ float Cs[4096];        // [d][n]
  __shared__ float Hs[64 * 68];     // [n][t]
  const int tid = threadIdx.x;
  const int t0 = blockIdx.x * 64;
  const int d0 = blockIdx.y * 64;
  const int tq = (tid & 15) * 4;
  const int dq = (tid >> 4) * 4;

#pragma unroll
  for (int it = 0; it < 4; ++it) {
    int idx = it * 256 + tid;
    int r = idx >> 4, c4 = (idx & 15) * 4;
    *(float4*)&Cs[r * 64 + c4] = *(const float4*)&C[(size_t)(d0 + r) * 64 + c4];
    float4 h = *(const float4*)&Ht[(size_t)(t0 + r) * 64 + c4];
    Hs[(c4 + 0) * 68 + r] = h.x;
    Hs[(c4 + 1) * 68 + r] = h.y;
    Hs[(c4 + 2) * 68 + r] = h.z;
    Hs[(c4 + 3) * 68 + r] = h.w;
  }
  __syncthreads();

  float acc[16];
  mmzero(acc);
#pragma unroll 4
  for (int n = 0; n < 64; n += 4) {
    float4 h0 = *(const float4*)&Hs[(n + 0) * 68 + tq];
    float4 h1 = *(const float4*)&Hs[(n + 1) * 68 + tq];
    float4 h2 = *(const float4*)&Hs[(n + 2) * 68 + tq];
    float4 h3 = *(const float4*)&Hs[(n + 3) * 68 + tq];
    float4 cv0 = *(const float4*)&Cs[(dq + 0) * 64 + n];
    float4 cv1 = *(const float4*)&Cs[(dq + 1) * 64 + n];
    float4 cv2 = *(const float4*)&Cs[(dq + 2) * 64 + n];
    float4 cv3 = *(const float4*)&Cs[(dq + 3) * 64 + n];
#define OROW(i, ci) \
    acc[i * 4 + 0] += ci.x * h0.x + ci.y * h1.x + ci.z * h2.x + ci.w * h3.x; \
    acc[i * 4 + 1] += ci.x * h0.y + ci.y * h1.y + ci.z * h2.y + ci.w * h3.y; \
    acc[i * 4 + 2] += ci.x * h0.z + ci.y * h1.z + ci.z * h2.z + ci.w * h3.z; \
    acc[i * 4 + 3] += ci.x * h0.w + ci.y * h1.w + ci.z * h2.w + ci.w * h3.w;
    OROW(0, cv0) OROW(1, cv1) OROW(2, cv2) OROW(3, cv3)
#undef OROW
  }

#pragma unroll
  for (int i = 0; i < 4; ++i) {
    int d = d0 + dq + i;
    size_t off = (size_t)d * LSEQ + t0 + tq;
    float4 x4 = *(const float4*)&X[off];
    float dp = Dp[d];
    *(float4*)&Y[off] = make_float4(acc[i * 4 + 0] + dp * x4.x,
                                    acc[i * 4 + 1] + dp * x4.y,
                                    acc[i * 4 + 2] + dp * x4.z,
                                    acc[i * 4 + 3] + dp * x4.w);
  }
}

// ---------------------------------------------------------------------------
extern "C" void kernel_launch(void* const* d_in, const int* in_sizes, int n_in,
                              void* d_out, int out_size, void* d_ws, size_t ws_size,
                              hipStream_t stream) {
  const float* X  = (const float*)d_in[0];
  const float* A  = (const float*)d_in[1];
  const float* B  = (const float*)d_in[2];
  const float* C  = (const float*)d_in[3];
  const float* Dp = (const float*)d_in[4];
  const float* ld = (const float*)d_in[5];
  float* out = (float*)d_out;
  float* ws = (float*)d_ws;

  float* invdT = ws;               // 4096
  float* dA    = ws + 4096;        // 4096
  float* dA32  = ws + 8192;        // 4096
  float* dA512 = ws + 12288;       // 4096
  float* Bt    = ws + 16384;       // 131072
  float* V     = ws + 147456;      // 524288  (reused as Ht later)
  float* U     = ws + 671744;      // 524288
  float* S     = ws + 1196032;     // 16384
  float* Hinit = ws + 1212416;     // 16384
  float* Ht    = V;                // overlay: V dead after u_transform
  // total 1228800 floats = 4.92 MB

  (void)hipMemsetAsync(V, 0, 524288 * sizeof(float), stream);
  bt_kernel<<<32, 256, 0, stream>>>(B, Bt);
  main_kernel<<<1 + NSLAB * 128, 256, 0, stream>>>(X, A, Bt, ld, invdT, dA, dA32,
                                                   dA512, V);
  u_transform<<<128, 256, 0, stream>>>(V, invdT, U);
  scan_kernel<T1, false, false><<<NC1, 64, 0, stream>>>(U, dA, nullptr, S);
  mid_kernel<<<1, 1024, 0, stream>>>(S, dA32, dA512, Hinit);
  scan_kernel<T1, true, false><<<NC1, 64, 0, stream>>>(U, dA, Hinit, Ht);
  out_kernel<<<dim3(128, 32), 256, 0, stream>>>(X, C, Dp, Ht, out);
}

// Round 6
// 261.084 us; speedup vs baseline: 1.9967x; 1.1333x over previous
//
#include <hip/hip_runtime.h>
#include <math.h>

#define D_CH 2048
#define LSEQ 8192
#define T1 32
#define NC1 256          // LSEQ / T1
#define VSLAB 524288     // per-slab V floats (8192*64)

typedef __attribute__((ext_vector_type(8))) short bf16x8;
typedef __attribute__((ext_vector_type(4))) float f32x4;

__device__ __forceinline__ short f2bf(float x) {
  unsigned u = __float_as_uint(x);
  u += 0x7FFFu + ((u >> 16) & 1);       // round-to-nearest-even
  return (short)(u >> 16);
}

// ---------------------------------------------------------------------------
// fp32 4x4-register-tile 64x64 matmul helpers on LDS (numerically critical
// dA-power chain stays fp32: squaring DOUBLES relative exponent error, so
// bf16 squarings diverge — measured round 5: 65% output error).
// ---------------------------------------------------------------------------
__device__ __forceinline__ void mmzero(float acc[16]) {
#pragma unroll
  for (int t = 0; t < 16; ++t) acc[t] = 0.f;
}

template <int SZ>
__device__ __forceinline__ void mmld(float acc[16], const float* __restrict__ Z,
                                     int r0, int c0) {
#pragma unroll
  for (int i = 0; i < 4; ++i) {
    float4 z = *(const float4*)&Z[(r0 + i) * SZ + c0];
    acc[i * 4 + 0] = z.x; acc[i * 4 + 1] = z.y;
    acc[i * 4 + 2] = z.z; acc[i * 4 + 3] = z.w;
  }
}

template <int SX, int SY>
__device__ __forceinline__ void mac44(float acc[16], const float* __restrict__ Xb,
                                      const float* __restrict__ Yb, int r0, int c0) {
#pragma unroll 4
  for (int k = 0; k < 64; k += 4) {
    float4 x0 = *(const float4*)&Xb[(r0 + 0) * SX + k];
    float4 x1 = *(const float4*)&Xb[(r0 + 1) * SX + k];
    float4 x2 = *(const float4*)&Xb[(r0 + 2) * SX + k];
    float4 x3 = *(const float4*)&Xb[(r0 + 3) * SX + k];
    float4 y0 = *(const float4*)&Yb[(k + 0) * SY + c0];
    float4 y1 = *(const float4*)&Yb[(k + 1) * SY + c0];
    float4 y2 = *(const float4*)&Yb[(k + 2) * SY + c0];
    float4 y3 = *(const float4*)&Yb[(k + 3) * SY + c0];
#define MROW(i, xi) \
    acc[i * 4 + 0] += xi.x * y0.x + xi.y * y1.x + xi.z * y2.x + xi.w * y3.x; \
    acc[i * 4 + 1] += xi.x * y0.y + xi.y * y1.y + xi.z * y2.y + xi.w * y3.y; \
    acc[i * 4 + 2] += xi.x * y0.z + xi.y * y1.z + xi.z * y2.z + xi.w * y3.z; \
    acc[i * 4 + 3] += xi.x * y0.w + xi.y * y1.w + xi.z * y2.w + xi.w * y3.w;
    MROW(0, x0) MROW(1, x1) MROW(2, x2) MROW(3, x3)
#undef MROW
  }
}

template <int SZ>
__device__ __forceinline__ void mmst(float* Dst, const float acc[16], int r0, int c0) {
#pragma unroll
  for (int i = 0; i < 4; ++i)
    *(float4*)&Dst[(r0 + i) * SZ + c0] =
        make_float4(acc[i * 4 + 0], acc[i * 4 + 1], acc[i * 4 + 2], acc[i * 4 + 3]);
}

// ---------------------------------------------------------------------------
// main_kernel:
//   block 0: prep — fp32 Q-chain -> invdT (delta*Q^T), dA = 2Q-I
//   blocks 1..: V[slab] = B @ X  (bf16 MFMA, 64t x 64n tiles, K-slab)
// ---------------------------------------------------------------------------
__global__ __launch_bounds__(256) void main_kernel(const float* __restrict__ X,
                                                   const float* __restrict__ A,
                                                   const float* __restrict__ B,
                                                   const float* __restrict__ logd,
                                                   float* __restrict__ invdT,
                                                   float* __restrict__ dAg,
                                                   float* __restrict__ V,
                                                   int KS) {
  __shared__ float smem[13056];          // 52.2 KB union
  const int tid = threadIdx.x;
  const int lane = tid & 63;
  const int w = tid >> 6;

  if (blockIdx.x == 0) {
    // ---------------- Q-chain (fp32): Q ~= inv(I - P), ||P|| <= ~0.12 ------
    float* b0 = smem;
    float* b1 = smem + 4352;
    float* b2 = smem + 8704;
    const int r0 = (tid >> 4) * 4, c0 = (tid & 15) * 4;
    const float delta = expf(logd[0]);
    const float half = 0.5f * delta;
    float acc[16], acc2[16];

    for (int idx = tid; idx < 4096; idx += 256) {
      int i = idx >> 6, j = idx & 63;
      float p = half * A[idx];
      b0[i * 68 + j] = p;
      b2[i * 68 + j] = p + (i == j ? 1.f : 0.f);
    }
    __syncthreads();
    // b1 = P^2
    mmzero(acc); mac44<68, 68>(acc, b0, b0, r0, c0); mmst<68>(b1, acc, r0, c0);
    __syncthreads();
    // Q2 = Q1 + P2*Q1 -> b0 ; P4 -> b2
    mmld<68>(acc, b2, r0, c0); mac44<68, 68>(acc, b1, b2, r0, c0);
    mmzero(acc2); mac44<68, 68>(acc2, b1, b1, r0, c0);
    __syncthreads();
    mmst<68>(b0, acc, r0, c0); mmst<68>(b2, acc2, r0, c0);
    __syncthreads();
    // Q4 -> b1 ; P8 -> b2
    mmld<68>(acc, b0, r0, c0); mac44<68, 68>(acc, b2, b0, r0, c0);
    mmzero(acc2); mac44<68, 68>(acc2, b2, b2, r0, c0);
    __syncthreads();
    mmst<68>(b1, acc, r0, c0); mmst<68>(b2, acc2, r0, c0);
    __syncthreads();
    // Q8 -> b0
    mmld<68>(acc, b1, r0, c0); mac44<68, 68>(acc, b2, b1, r0, c0);
    __syncthreads();
    mmst<68>(b0, acc, r0, c0);
    __syncthreads();

    // exports: invdT = delta*Q^T, dA = 2Q - I
    for (int idx = tid; idx < 4096; idx += 256) {
      int n = idx >> 6, m = idx & 63;
      float qv = b0[n * 68 + m];
      invdT[m * 64 + n] = delta * qv;
      dAg[idx] = 2.f * qv - (n == m ? 1.f : 0.f);
    }
    return;
  }

  // ------------------------------ vgemm (bf16 MFMA) ------------------------
  const int b = blockIdx.x - 1;
  const int t0 = (b & 127) << 6;
  const int slab = b >> 7;
  const int k0 = slab * KS;
  short* Xs = (short*)smem;              // [t][k] bf16, stride 72
  short* Bs = (short*)smem + 4608;       // [n][k] bf16, stride 72
  const int q = lane >> 4, r = lane & 15;

  f32x4 acc[4];
#pragma unroll
  for (int j = 0; j < 4; ++j) acc[j] = (f32x4){0.f, 0.f, 0.f, 0.f};

  const int brow = (lane >> 3);          // 0..7
  const int bkc = (lane & 7) * 8;        // 0..56

  for (int kk = 0; kk < KS; kk += 64) {
    float xv[16];
    float bv[16];
    // X: lane = t (coalesced); wave w pass p covers k = p*32 + w*8 + j
#pragma unroll
    for (int p = 0; p < 2; ++p)
#pragma unroll
      for (int j = 0; j < 8; ++j)
        xv[p * 8 + j] = X[(size_t)(k0 + kk + p * 32 + w * 8 + j) * LSEQ + t0 + lane];
    // B: row n = p*32 + w*8 + (lane>>3); 8 consecutive k per lane
#pragma unroll
    for (int p = 0; p < 2; ++p) {
      int n = p * 32 + w * 8 + brow;
      float4 f0 = *(const float4*)&B[(size_t)n * D_CH + k0 + kk + bkc];
      float4 f1 = *(const float4*)&B[(size_t)n * D_CH + k0 + kk + bkc + 4];
      bv[p * 8 + 0] = f0.x; bv[p * 8 + 1] = f0.y; bv[p * 8 + 2] = f0.z; bv[p * 8 + 3] = f0.w;
      bv[p * 8 + 4] = f1.x; bv[p * 8 + 5] = f1.y; bv[p * 8 + 6] = f1.z; bv[p * 8 + 7] = f1.w;
    }
    __syncthreads();
#pragma unroll
    for (int p = 0; p < 2; ++p) {
      bf16x8 xp, bp;
#pragma unroll
      for (int j = 0; j < 8; ++j) { xp[j] = f2bf(xv[p * 8 + j]); bp[j] = f2bf(bv[p * 8 + j]); }
      *(bf16x8*)&Xs[lane * 72 + p * 32 + w * 8] = xp;
      *(bf16x8*)&Bs[(p * 32 + w * 8 + brow) * 72 + bkc] = bp;
    }
    __syncthreads();
#pragma unroll
    for (int ks = 0; ks < 64; ks += 32) {
      bf16x8 a = *(const bf16x8*)&Xs[(w * 16 + r) * 72 + ks + q * 8];
#pragma unroll
      for (int j = 0; j < 4; ++j) {
        bf16x8 bb = *(const bf16x8*)&Bs[(j * 16 + r) * 72 + ks + q * 8];
        acc[j] = __builtin_amdgcn_mfma_f32_16x16x32_bf16(a, bb, acc[j], 0, 0, 0);
      }
    }
  }
  float* Vs = V + (size_t)slab * VSLAB;
#pragma unroll
  for (int j = 0; j < 4; ++j)
#pragma unroll
    for (int reg = 0; reg < 4; ++reg)
      Vs[(size_t)(t0 + w * 16 + q * 4 + reg) * 64 + j * 16 + r] = acc[j][reg];
}

// ---------------------------------------------------------------------------
// matvec step: h' = M h + u, h broadcast via LDS ping-pong
// ---------------------------------------------------------------------------
__device__ __forceinline__ float matvec(const float ar[64], const float* __restrict__ hb,
                                        float u) {
  float a0 = u, a1 = 0.f, a2 = 0.f, a3 = 0.f;
#pragma unroll
  for (int jj = 0; jj < 64; jj += 4) {
    float4 hv = *(const float4*)&hb[jj];
    a0 += ar[jj + 0] * hv.x;
    a1 += ar[jj + 1] * hv.y;
    a2 += ar[jj + 2] * hv.z;
    a3 += ar[jj + 3] * hv.w;
  }
  return (a0 + a1) + (a2 + a3);
}

// ---------------------------------------------------------------------------
// scan1: blocks 0..NC1-1: U-chunk = invd applied to sum of V slabs, then
// wave 0 does the serial 32-step chunk summary.
// block NC1: 9 fp32 squarings of dA -> dA^32, dA^512 (for mid, next launch).
// ---------------------------------------------------------------------------
__global__ __launch_bounds__(256) void scan1_kernel(const float* __restrict__ V,
                                                    const float* __restrict__ invdT,
                                                    const float* __restrict__ dA,
                                                    float* __restrict__ U,
                                                    float* __restrict__ S,
                                                    float* __restrict__ dA32g,
                                                    float* __restrict__ dA512g,
                                                    int nslab) {
  __shared__ float smem[8704];
  const int tid = threadIdx.x;
  const int c = blockIdx.x;

  if (c == NC1) {
    // fp32 squaring chain (numerically critical — see header comment)
    float* b0 = smem;
    float* b1 = smem + 4352;
    const int r0 = (tid >> 4) * 4, c0 = (tid & 15) * 4;
    for (int idx = tid; idx < 4096; idx += 256)
      b0[(idx >> 6) * 68 + (idx & 63)] = dA[idx];
    __syncthreads();
    float acc[16];
    float* p = b0; float* q = b1;
    for (int s = 1; s <= 9; ++s) {
      mmzero(acc); mac44<68, 68>(acc, p, p, r0, c0);
      if (s == 5) mmst<64>(dA32g, acc, r0, c0);
      if (s == 9) mmst<64>(dA512g, acc, r0, c0);
      mmst<68>(q, acc, r0, c0);
      __syncthreads();
      float* t = p; p = q; q = t;
    }
    return;
  }

  float* invs = smem;            // 4096
  float* Vs   = smem + 4096;     // 2048
  float* Us   = smem + 6144;     // 2048
  float* hs0  = smem + 8192;     // 64
  float* hs1  = smem + 8256;     // 64

  for (int idx = tid; idx < 4096; idx += 256) invs[idx] = invdT[idx];
  for (int idx = tid; idx < 2048; idx += 256) {
    float v = 0.f;
    for (int s = 0; s < nslab; ++s) v += V[(size_t)s * VSLAB + (size_t)c * 2048 + idx];
    Vs[idx] = v;
  }
  __syncthreads();

  // transform: 2 rows x 4 cols per thread
  const int r0 = (tid >> 4) * 2, c0 = (tid & 15) * 4;
  float a0[4] = {0.f, 0.f, 0.f, 0.f}, a1[4] = {0.f, 0.f, 0.f, 0.f};
#pragma unroll 4
  for (int k = 0; k < 64; k += 4) {
    float4 v0 = *(const float4*)&Vs[r0 * 64 + k];
    float4 v1 = *(const float4*)&Vs[(r0 + 1) * 64 + k];
    float4 y0 = *(const float4*)&invs[(k + 0) * 64 + c0];
    float4 y1 = *(const float4*)&invs[(k + 1) * 64 + c0];
    float4 y2 = *(const float4*)&invs[(k + 2) * 64 + c0];
    float4 y3 = *(const float4*)&invs[(k + 3) * 64 + c0];
    a0[0] += v0.x * y0.x + v0.y * y1.x + v0.z * y2.x + v0.w * y3.x;
    a0[1] += v0.x * y0.y + v0.y * y1.y + v0.z * y2.y + v0.w * y3.y;
    a0[2] += v0.x * y0.z + v0.y * y1.z + v0.z * y2.z + v0.w * y3.z;
    a0[3] += v0.x * y0.w + v0.y * y1.w + v0.z * y2.w + v0.w * y3.w;
    a1[0] += v1.x * y0.x + v1.y * y1.x + v1.z * y2.x + v1.w * y3.x;
    a1[1] += v1.x * y0.y + v1.y * y1.y + v1.z * y2.y + v1.w * y3.y;
    a1[2] += v1.x * y0.z + v1.y * y1.z + v1.z * y2.z + v1.w * y3.z;
    a1[3] += v1.x * y0.w + v1.y * y1.w + v1.z * y2.w + v1.w * y3.w;
  }
  *(float4*)&Us[r0 * 64 + c0] = make_float4(a0[0], a0[1], a0[2], a0[3]);
  *(float4*)&Us[(r0 + 1) * 64 + c0] = make_float4(a1[0], a1[1], a1[2], a1[3]);
  *(float4*)&U[(size_t)(c * 32 + r0) * 64 + c0] = make_float4(a0[0], a0[1], a0[2], a0[3]);
  *(float4*)&U[(size_t)(c * 32 + r0 + 1) * 64 + c0] = make_float4(a1[0], a1[1], a1[2], a1[3]);
  __syncthreads();

  if (tid < 64) {
    float ar[64];
#pragma unroll
    for (int jj = 0; jj < 64; jj += 4) {
      float4 v = *(const float4*)&dA[tid * 64 + jj];
      ar[jj] = v.x; ar[jj + 1] = v.y; ar[jj + 2] = v.z; ar[jj + 3] = v.w;
    }
    float h = 0.f;
    hs0[tid] = 0.f;
    for (int t = 0; t < T1; ++t) {
      float u = Us[t * 64 + tid];
      h = matvec(ar, (t & 1) ? hs1 : hs0, u);
      ((t & 1) ? hs0 : hs1)[tid] = h;
    }
    S[c * 64 + tid] = h;
  }
}

// ---------------------------------------------------------------------------
// mid: 3 middle levels in one block (16 waves), round-4 proven.
// ---------------------------------------------------------------------------
__global__ __launch_bounds__(1024) void mid_kernel(const float* __restrict__ S,
                                                   const float* __restrict__ dA32,
                                                   const float* __restrict__ dA512,
                                                   float* __restrict__ Hinit) {
  __shared__ float S2s[1024];
  __shared__ float H2s[1024];
  __shared__ float hsbuf[2048];
  const int tid = threadIdx.x;
  const int wave = tid >> 6, lane = tid & 63;
  float* hs0 = &hsbuf[wave * 128];
  float* hs1 = hs0 + 64;
  float ar[64];
#pragma unroll
  for (int jj = 0; jj < 64; jj += 4) {
    float4 v = *(const float4*)&dA32[lane * 64 + jj];
    ar[jj] = v.x; ar[jj + 1] = v.y; ar[jj + 2] = v.z; ar[jj + 3] = v.w;
  }
  const float* inw = S + wave * 16 * 64;

  float h = 0.f;
  hs0[lane] = 0.f;
  for (int t = 0; t < 16; ++t) {
    float u = inw[t * 64 + lane];
    h = matvec(ar, (t & 1) ? hs1 : hs0, u);
    ((t & 1) ? hs0 : hs1)[lane] = h;
  }
  S2s[wave * 64 + lane] = h;
  __syncthreads();

  if (wave == 0) {
    float br[64];
#pragma unroll
    for (int jj = 0; jj < 64; jj += 4) {
      float4 v = *(const float4*)&dA512[lane * 64 + jj];
      br[jj] = v.x; br[jj + 1] = v.y; br[jj + 2] = v.z; br[jj + 3] = v.w;
    }
    float g = 0.f;
    hs0[lane] = 0.f;
    for (int t = 0; t < 16; ++t) {
      H2s[t * 64 + lane] = g;
      float u = S2s[t * 64 + lane];
      g = matvec(br, (t & 1) ? hs1 : hs0, u);
      ((t & 1) ? hs0 : hs1)[lane] = g;
    }
  }
  __syncthreads();

  h = H2s[wave * 64 + lane];
  hs0[lane] = h;
  for (int t = 0; t < 16; ++t) {
    Hinit[(wave * 16 + t) * 64 + lane] = h;
    float u = inw[t * 64 + lane];
    h = matvec(ar, (t & 1) ? hs1 : hs0, u);
    ((t & 1) ? hs0 : hs1)[lane] = h;
  }
}

// ---------------------------------------------------------------------------
// scan2: one wave/block, full-state expansion with 4-deep prefetch ring.
// ---------------------------------------------------------------------------
__global__ __launch_bounds__(64) void scan2_kernel(const float* __restrict__ U,
                                                   const float* __restrict__ dA,
                                                   const float* __restrict__ Hinit,
                                                   float* __restrict__ Ht) {
  __shared__ float hs[2][64];
  const int tid = threadIdx.x;
  const int c = blockIdx.x;
  float ar[64];
#pragma unroll
  for (int jj = 0; jj < 64; jj += 4) {
    float4 v = *(const float4*)&dA[tid * 64 + jj];
    ar[jj] = v.x; ar[jj + 1] = v.y; ar[jj + 2] = v.z; ar[jj + 3] = v.w;
  }
  float h = Hinit[c * 64 + tid];
  hs[0][tid] = h;
  const float* inc = U + (size_t)c * T1 * 64;
  float* outc = Ht + (size_t)c * T1 * 64;
  float up[4];
#pragma unroll
  for (int i = 0; i < 4; ++i) up[i] = inc[i * 64 + tid];

  for (int t = 0; t < T1; ++t) {
    float u = up[t & 3];
    if (t + 4 < T1) up[t & 3] = inc[(t + 4) * 64 + tid];
    h = matvec(ar, hs[t & 1], u);
    hs[(t + 1) & 1][tid] = h;
    outc[t * 64 + tid] = h;
  }
}

// ---------------------------------------------------------------------------
// out: Y[d][t] = (C @ Ht^T)[d][t] + Dp[d]*X[d][t]  via bf16 MFMA (K = 64).
// ---------------------------------------------------------------------------
__global__ __launch_bounds__(256) void out_kernel(const float* __restrict__ X,
                                                  const float* __restrict__ C,
                                                  const float* __restrict__ Dp,
                                                  const float* __restrict__ Ht,
                                                  float* __restrict__ Y) {
  __shared__ short Cs[64 * 72];      // [d][n] bf16
  __shared__ short Hs[64 * 72];      // [t][n] bf16
  const int tid = threadIdx.x;
  const int lane = tid & 63, w = tid >> 6;
  const int t0 = blockIdx.x * 64;
  const int d0 = blockIdx.y * 64;
  const int q = lane >> 4, r = lane & 15;
  const int brow = lane >> 3, bkc = (lane & 7) * 8;

#pragma unroll
  for (int p = 0; p < 2; ++p) {
    int row = p * 32 + w * 8 + brow;
    float4 c0 = *(const float4*)&C[(size_t)(d0 + row) * 64 + bkc];
    float4 c1 = *(const float4*)&C[(size_t)(d0 + row) * 64 + bkc + 4];
    float4 h0 = *(const float4*)&Ht[(size_t)(t0 + row) * 64 + bkc];
    float4 h1 = *(const float4*)&Ht[(size_t)(t0 + row) * 64 + bkc + 4];
    bf16x8 cv, hv;
    cv[0] = f2bf(c0.x); cv[1] = f2bf(c0.y); cv[2] = f2bf(c0.z); cv[3] = f2bf(c0.w);
    cv[4] = f2bf(c1.x); cv[5] = f2bf(c1.y); cv[6] = f2bf(c1.z); cv[7] = f2bf(c1.w);
    hv[0] = f2bf(h0.x); hv[1] = f2bf(h0.y); hv[2] = f2bf(h0.z); hv[3] = f2bf(h0.w);
    hv[4] = f2bf(h1.x); hv[5] = f2bf(h1.y); hv[6] = f2bf(h1.z); hv[7] = f2bf(h1.w);
    *(bf16x8*)&Cs[row * 72 + bkc] = cv;
    *(bf16x8*)&Hs[row * 72 + bkc] = hv;
  }
  __syncthreads();

  f32x4 acc[4];
#pragma unroll
  for (int j = 0; j < 4; ++j) acc[j] = (f32x4){0.f, 0.f, 0.f, 0.f};
#pragma unroll
  for (int ks = 0; ks < 64; ks += 32) {
    bf16x8 a = *(const bf16x8*)&Cs[(w * 16 + r) * 72 + ks + q * 8];
#pragma unroll
    for (int j = 0; j < 4; ++j) {
      bf16x8 bb = *(const bf16x8*)&Hs[(j * 16 + r) * 72 + ks + q * 8];
      acc[j] = __builtin_amdgcn_mfma_f32_16x16x32_bf16(a, bb, acc[j], 0, 0, 0);
    }
  }

#pragma unroll
  for (int reg = 0; reg < 4; ++reg) {
    int d = d0 + w * 16 + q * 4 + reg;
    float dp = Dp[d];
#pragma unroll
    for (int j = 0; j < 4; ++j) {
      int t = t0 + j * 16 + r;
      size_t off = (size_t)d * LSEQ + t;
      Y[off] = acc[j][reg] + dp * X[off];
    }
  }
}

// ---------------------------------------------------------------------------
extern "C" void kernel_launch(void* const* d_in, const int* in_sizes, int n_in,
                              void* d_out, int out_size, void* d_ws, size_t ws_size,
                              hipStream_t stream) {
  const float* X  = (const float*)d_in[0];
  const float* A  = (const float*)d_in[1];
  const float* B  = (const float*)d_in[2];
  const float* Cm = (const float*)d_in[3];
  const float* Dp = (const float*)d_in[4];
  const float* ld = (const float*)d_in[5];
  float* out = (float*)d_out;
  float* ws = (float*)d_ws;

  // 4 K-slabs if workspace allows (10.2 MB), else 2 (6.2 MB)
  const size_t need4 = (size_t)(16384 + 4 * VSLAB + VSLAB + 16384 + 16384) * 4;
  const int nslab = (ws_size >= need4) ? 4 : 2;

  float* invdT = ws;                       // 4096
  float* dA    = ws + 4096;                // 4096
  float* dA32  = ws + 8192;                // 4096
  float* dA512 = ws + 12288;               // 4096
  float* V     = ws + 16384;               // nslab * 524288
  float* U     = V + (size_t)nslab * VSLAB; // 524288
  float* S     = U + VSLAB;                // 16384
  float* Hinit = S + 16384;                // 16384
  float* Ht    = V;                         // overlay: V dead after scan1

  main_kernel<<<nslab * 128 + 1, 256, 0, stream>>>(X, A, B, ld, invdT, dA, V,
                                                   2048 / nslab);
  scan1_kernel<<<NC1 + 1, 256, 0, stream>>>(V, invdT, dA, U, S, dA32, dA512, nslab);
  mid_kernel<<<1, 1024, 0, stream>>>(S, dA32, dA512, Hinit);
  scan2_kernel<<<NC1, 64, 0, stream>>>(U, dA, Hinit, Ht);
  out_kernel<<<dim3(128, 32), 256, 0, stream>>>(X, Cm, Dp, Ht, out);
}